// Round 1
// baseline (237.565 us; speedup 1.0000x reference)
//
#include <hip/hip_runtime.h>

// LIF forward: X [B, T, N] fp32 -> spikes [B, T, N] fp32
// B=128, T=32, N=8192. Recurrence per (b,n):
//   mem = mem + (x - mem)/TAU   (TAU=2, V_RESET=0)
//   spike = (mem - 1 > 0) ? 1 : 0
//   mem = spike ? 0 : mem
// Memory-bound: 268 MB traffic, ~43 us at 6.3 TB/s.

#define T_STEPS 32

__global__ __launch_bounds__(256) void lif_fwd_kernel(
    const float4* __restrict__ X, float4* __restrict__ out,
    int N4 /* N/4 */, int TN4 /* T*N/4 */)
{
    const int idx = blockIdx.x * blockDim.x + threadIdx.x;  // over B * N4
    const int b = idx / N4;        // N4 = 2048 (power of 2 -> shifts)
    const int n = idx - b * N4;
    const size_t base = (size_t)b * (size_t)TN4 + (size_t)n;

    float m0 = 0.f, m1 = 0.f, m2 = 0.f, m3 = 0.f;

#pragma unroll
    for (int t = 0; t < T_STEPS; ++t) {
        const float4 x = X[base + (size_t)t * (size_t)N4];

        // exact reference order: mem += (x - mem) * 0.5 ; threshold at 1.0
        m0 = m0 + (x.x - m0) * 0.5f;
        m1 = m1 + (x.y - m1) * 0.5f;
        m2 = m2 + (x.z - m2) * 0.5f;
        m3 = m3 + (x.w - m3) * 0.5f;

        float4 s;
        s.x = (m0 - 1.0f > 0.0f) ? 1.0f : 0.0f;
        s.y = (m1 - 1.0f > 0.0f) ? 1.0f : 0.0f;
        s.z = (m2 - 1.0f > 0.0f) ? 1.0f : 0.0f;
        s.w = (m3 - 1.0f > 0.0f) ? 1.0f : 0.0f;

        // hard reset to 0 where spiked
        m0 = (s.x != 0.0f) ? 0.0f : m0;
        m1 = (s.y != 0.0f) ? 0.0f : m1;
        m2 = (s.z != 0.0f) ? 0.0f : m2;
        m3 = (s.w != 0.0f) ? 0.0f : m3;

        out[base + (size_t)t * (size_t)N4] = s;
    }
}

extern "C" void kernel_launch(void* const* d_in, const int* in_sizes, int n_in,
                              void* d_out, int out_size, void* d_ws, size_t ws_size,
                              hipStream_t stream) {
    const float4* X = (const float4*)d_in[0];
    float4* out = (float4*)d_out;

    // in_sizes[0] = B*T*N = 33554432 ; N = 8192, T = 32
    const int N = 8192;
    const int T = T_STEPS;
    const int total = in_sizes[0];          // B*T*N
    const int B = total / (T * N);          // 128

    const int N4 = N / 4;                   // 2048
    const int TN4 = T * N4;                 // 65536
    const int threads = B * N4;             // 262144

    const int block = 256;
    const int grid = (threads + block - 1) / block;  // 1024

    lif_fwd_kernel<<<grid, block, 0, stream>>>(X, out, N4, TN4);
}